// Round 4
// baseline (35.616 us; speedup 1.0000x reference)
//
#include <hip/hip_runtime.h>

// SingleCurveDeformLayer: 2-step Euler RBF flow, FUSED single kernel.
//   Phase A: shape1_i = land_i + TAU*sum_j exp(-|land_i - src_j|^2/s2)*mom_j   (all 2N i per batch)
//   [grid barrier]
//   Phase B: out_i    = shape1_i + TAU*sum_j exp(-|shape1_i - shape1_j|^2/s2)*mom_j  (N targets)
//
// 256 blocks x 512 threads; LDS 32KB/block -> max 5 blocks/CU so all 256 are
// co-resident on 256 CUs -> manual grid barrier is deadlock-free.
// Cross-XCD visibility of shape1 (written on one XCD, read on another) is
// guaranteed by agent-scope 8B atomics (coherence-point ops), per G16.
// Barrier counter lives in d_ws and is reset each call by hipMemsetAsync.

typedef unsigned long long u64;

constexpr int N     = 2048;   // n_src == n_tgt
constexpr int TPB   = 512;    // 8 waves
constexpr int NBLK  = 256;
constexpr float TAU   = 0.5f;            // 1/(N_T-1), N_T=3
constexpr float LOG2E = 1.44269504088896340736f;

union F2U { float2 f; u64 u; };

__device__ inline void store_f2_agent(float* p, float x, float y) {
    F2U v; v.f = make_float2(x, y);
    __hip_atomic_store((u64*)p, v.u, __ATOMIC_RELAXED, __HIP_MEMORY_SCOPE_AGENT);
}
__device__ inline float2 load_f2_agent(const float* p) {
    F2U v; v.u = __hip_atomic_load((const u64*)p, __ATOMIC_RELAXED, __HIP_MEMORY_SCOPE_AGENT);
    return v.f;
}

__device__ inline float fast_exp2(float x) {
    return __builtin_amdgcn_exp2f(x);   // v_exp_f32
}

__global__ __launch_bounds__(TPB)
void deform_fused(const float* __restrict__ momentum,
                  const float* __restrict__ source_init,
                  const float* __restrict__ target_init,
                  const float* __restrict__ sigmaV2,
                  float* __restrict__ shape1,        // ws: [B][2N][2]
                  unsigned* __restrict__ barrier_cnt,
                  float* __restrict__ out,           // [B][N][2]
                  int B)
{
    __shared__ float4 sj[N];   // (x, y, TAU*mx, TAU*my): 32 KB

    const int tid  = threadIdx.x;
    const int bpb  = NBLK / B;              // blocks per batch (64 for B=4)
    const int b    = blockIdx.x / bpb;
    const int pblk = blockIdx.x % bpb;

    const float c1 = -LOG2E / sigmaV2[0];   // exp(-d2/s2) = exp2(d2 * c1)

    const int c = tid & 31;                 // j-chunk lane (32-way j split)
    const int g = tid >> 5;                 // point-group (0..15)

    // ======== Phase A: shape1 for all 2N landmarks (64 points/block) ========
    for (int k2 = tid; k2 < N / 2; k2 += TPB) {          // 2 iters, float4 = 2 pts
        const float4 p = ((const float4*)source_init)[b * (N / 2) + k2];
        const float4 m = ((const float4*)momentum  )[b * (N / 2) + k2];
        sj[2 * k2 + 0] = make_float4(p.x, p.y, m.x * TAU, m.y * TAU);
        sj[2 * k2 + 1] = make_float4(p.z, p.w, m.z * TAU, m.w * TAU);
    }

    const int piA0 = pblk * 64 + g * 4;     // this lane's 4 i-points
    float xiA[4], yiA[4];
    #pragma unroll
    for (int m = 0; m < 4; ++m) {
        const int pi = piA0 + m;            // block-uniform branch (64 | N)
        const float2 p = (pi < N)
            ? ((const float2*)source_init)[b * N + pi]
            : ((const float2*)target_init)[b * N + (pi - N)];
        xiA[m] = p.x; yiA[m] = p.y;
    }
    __syncthreads();

    float ax[4] = {0, 0, 0, 0}, ay[4] = {0, 0, 0, 0};
    #pragma unroll 2
    for (int t = 0; t < N / 32; ++t) {
        const float4 s = sj[t * 32 + c];
        #pragma unroll
        for (int m = 0; m < 4; ++m) {
            const float dx = xiA[m] - s.x;
            const float dy = yiA[m] - s.y;
            const float w  = fast_exp2(fmaf(dy, dy, dx * dx) * c1);
            ax[m] = fmaf(w, s.z, ax[m]);
            ay[m] = fmaf(w, s.w, ay[m]);
        }
    }
    #pragma unroll
    for (int m = 0; m < 4; ++m) {
        #pragma unroll
        for (int d = 1; d < 32; d <<= 1) {
            ax[m] += __shfl_xor(ax[m], d);
            ay[m] += __shfl_xor(ay[m], d);
        }
    }
    if (c == 0) {
        #pragma unroll
        for (int m = 0; m < 4; ++m) {
            const int pi = piA0 + m;
            store_f2_agent(&shape1[(b * 2 * N + pi) * 2], xiA[m] + ax[m], yiA[m] + ay[m]);
        }
    }

    // ======== grid barrier (all 256 blocks co-resident) ========
    __syncthreads();
    if (tid == 0) {
        __hip_atomic_fetch_add(barrier_cnt, 1u, __ATOMIC_ACQ_REL, __HIP_MEMORY_SCOPE_AGENT);
        while (__hip_atomic_load(barrier_cnt, __ATOMIC_ACQUIRE, __HIP_MEMORY_SCOPE_AGENT)
               < (unsigned)NBLK) {
            __builtin_amdgcn_s_sleep(1);
        }
    }
    __syncthreads();

    // ======== Phase B: out for N targets (32 points/block) ========
    for (int k = tid; k < N; k += TPB) {                 // 4 iters
        const float2 p = load_f2_agent(&shape1[(b * 2 * N + k) * 2]);
        const float2 m = ((const float2*)momentum)[b * N + k];
        sj[k] = make_float4(p.x, p.y, m.x * TAU, m.y * TAU);
    }
    const int piB0 = pblk * 32 + g * 2;
    float xiB[2], yiB[2];
    #pragma unroll
    for (int m = 0; m < 2; ++m) {
        const float2 p = load_f2_agent(&shape1[(b * 2 * N + N + piB0 + m) * 2]);
        xiB[m] = p.x; yiB[m] = p.y;
    }
    __syncthreads();

    float bx[2] = {0, 0}, by[2] = {0, 0};
    #pragma unroll 2
    for (int t = 0; t < N / 32; ++t) {
        const float4 s = sj[t * 32 + c];
        #pragma unroll
        for (int m = 0; m < 2; ++m) {
            const float dx = xiB[m] - s.x;
            const float dy = yiB[m] - s.y;
            const float w  = fast_exp2(fmaf(dy, dy, dx * dx) * c1);
            bx[m] = fmaf(w, s.z, bx[m]);
            by[m] = fmaf(w, s.w, by[m]);
        }
    }
    #pragma unroll
    for (int m = 0; m < 2; ++m) {
        #pragma unroll
        for (int d = 1; d < 32; d <<= 1) {
            bx[m] += __shfl_xor(bx[m], d);
            by[m] += __shfl_xor(by[m], d);
        }
    }
    if (c == 0) {
        #pragma unroll
        for (int m = 0; m < 2; ++m) {
            const int pi = piB0 + m;
            ((float2*)out)[b * N + pi] = make_float2(xiB[m] + bx[m], yiB[m] + by[m]);
        }
    }
}

extern "C" void kernel_launch(void* const* d_in, const int* in_sizes, int n_in,
                              void* d_out, int out_size, void* d_ws, size_t ws_size,
                              hipStream_t stream)
{
    const float* momentum    = (const float*)d_in[0];
    const float* source_init = (const float*)d_in[1];
    const float* target_init = (const float*)d_in[2];
    const float* sigmaV2     = (const float*)d_in[3];
    float* out = (float*)d_out;

    const int B = in_sizes[0] / (N * 2);        // 4

    float*    shape1      = (float*)d_ws;                        // B*2N*2 floats = 128 KB
    unsigned* barrier_cnt = (unsigned*)((char*)d_ws + (size_t)B * 2 * N * 2 * sizeof(float));

    // reset barrier counter every call (graph-capture-legal, deterministic)
    (void)hipMemsetAsync(barrier_cnt, 0, sizeof(unsigned), stream);

    deform_fused<<<dim3(NBLK), dim3(TPB), 0, stream>>>(
        momentum, source_init, target_init, sigmaV2, shape1, barrier_cnt, out, B);
}

// Round 5
// 20.979 us; speedup vs baseline: 1.6977x; 1.6977x over previous
//
#include <hip/hip_runtime.h>

// SingleCurveDeformLayer: 2-step Euler RBF flow, two kernels (best structure).
//   step1: shape1_i = land_i + TAU*sum_j exp(-|land_i - src_j|^2/s2)*mom_j   (all 2N i)
//   step2: out_i    = shape1_i + TAU*sum_j exp(-|shape1_i-shape1_j|^2/s2)*mom_j  (tgt i)
//
// Decomposition: SPLIT=32 j-chunks per point-group, MP=2 points/lane,
// P=16 points/block (TPB=256, 4 waves). Grid: 1024 blocks step1, 512 step2
// -> 4 blocks/CU resident (LDS 32KB caps at 5) = 4 waves/SIMD for latency
// hiding (R2 ran only 2/SIMD).
// Coordinates pre-scaled by sqrt(log2e/sigma^2) so the pair weight is
// exp2(-(dx^2+dy^2)) -- negation is a free v_exp_f32 src modifier; TAU is
// folded into the staged momenta. 6 VALU + 1 trans per pair.

constexpr int N     = 2048;   // n_src == n_tgt
constexpr int TPB   = 256;    // 4 waves
constexpr int SPLIT = 32;     // j-chunks (lanes) per point-group
constexpr int MP    = 2;      // i-points per lane
constexpr int PPB   = (TPB / SPLIT) * MP;   // 16 points per block
constexpr int NJ    = N / SPLIT;            // 64 j-iterations per lane
constexpr float TAU   = 0.5f;               // 1/(N_T-1), N_T=3
constexpr float LOG2E = 1.44269504088896340736f;

__device__ inline float exp2_neg(float x) {        // 2^(-x), free neg modifier
    return __builtin_amdgcn_exp2f(-x);
}

template<int STEP>
__global__ __launch_bounds__(TPB)
void deform_kernel(const float* __restrict__ momentum,
                   const float* __restrict__ source_init,
                   const float* __restrict__ target_init,
                   const float* __restrict__ sigmaV2,
                   float* __restrict__ shape1,   // ws: [B][2N][2]
                   float* __restrict__ out)      // [B][N][2]
{
    __shared__ float4 sj[N];   // (s*x, s*y, TAU*mx, TAU*my): 32 KB

    const int tid  = threadIdx.x;
    const int ppb  = (STEP == 1) ? 2 * N : N;   // points per batch this step
    const int bpb  = ppb / PPB;                 // blocks per batch
    const int b    = blockIdx.x / bpb;
    const int pblk = blockIdx.x % bpb;

    const float scale = sqrtf(LOG2E / sigmaV2[0]);   // coord pre-scale

    // ---- stage source j-data into LDS (float4 = 2 points per load) ----
    for (int k4 = tid; k4 < N / 2; k4 += TPB) {      // 4 iters
        float4 p;
        if (STEP == 1) p = ((const float4*)source_init)[b * (N / 2) + k4];
        else           p = ((const float4*)(shape1 + (size_t)b * 2 * N * 2))[k4];
        const float4 m = ((const float4*)momentum)[b * (N / 2) + k4];
        sj[2 * k4 + 0] = make_float4(p.x * scale, p.y * scale, m.x * TAU, m.y * TAU);
        sj[2 * k4 + 1] = make_float4(p.z * scale, p.w * scale, m.z * TAU, m.w * TAU);
    }

    const int c   = tid & 31;            // j-chunk lane
    const int g   = tid >> 5;            // point-group (0..7)
    const int pi0 = pblk * PPB + g * MP; // lane's 2 consecutive points

    // ---- my i-positions (float4 = both points) ----
    float4 pin;
    if (STEP == 1) {
        if (pi0 < N) pin = ((const float4*)source_init)[(b * N + pi0) >> 1];
        else         pin = ((const float4*)target_init)[(b * N + (pi0 - N)) >> 1];
    } else {
        pin = ((const float4*)shape1)[(b * 2 * N + N + pi0) >> 1];
    }
    const float xs0 = pin.x * scale, ys0 = pin.y * scale;
    const float xs1 = pin.z * scale, ys1 = pin.w * scale;
    __syncthreads();

    float ax0 = 0.f, ay0 = 0.f, ax1 = 0.f, ay1 = 0.f;
    #pragma unroll 4
    for (int t = 0; t < NJ; ++t) {
        const float4 s = sj[t * 32 + c];
        {
            const float dx = xs0 - s.x, dy = ys0 - s.y;
            const float w  = exp2_neg(fmaf(dy, dy, dx * dx));
            ax0 = fmaf(w, s.z, ax0);  ay0 = fmaf(w, s.w, ay0);
        }
        {
            const float dx = xs1 - s.x, dy = ys1 - s.y;
            const float w  = exp2_neg(fmaf(dy, dy, dx * dx));
            ax1 = fmaf(w, s.z, ax1);  ay1 = fmaf(w, s.w, ay1);
        }
    }

    // ---- reduce across the 32 j-chunk lanes ----
    #pragma unroll
    for (int d = 1; d < 32; d <<= 1) {
        ax0 += __shfl_xor(ax0, d);  ay0 += __shfl_xor(ay0, d);
        ax1 += __shfl_xor(ax1, d);  ay1 += __shfl_xor(ay1, d);
    }

    if (c == 0) {
        const float4 o = make_float4(pin.x + ax0, pin.y + ay0,
                                     pin.z + ax1, pin.w + ay1);
        if (STEP == 1) ((float4*)shape1)[(b * 2 * N + pi0) >> 1] = o;
        else           ((float4*)out)[(b * N + pi0) >> 1] = o;
    }
}

extern "C" void kernel_launch(void* const* d_in, const int* in_sizes, int n_in,
                              void* d_out, int out_size, void* d_ws, size_t ws_size,
                              hipStream_t stream)
{
    const float* momentum    = (const float*)d_in[0];
    const float* source_init = (const float*)d_in[1];
    const float* target_init = (const float*)d_in[2];
    const float* sigmaV2     = (const float*)d_in[3];
    float* out    = (float*)d_out;
    float* shape1 = (float*)d_ws;   // B * 4096 * 2 floats = 128 KB

    const int B = in_sizes[0] / (N * 2);   // 4

    dim3 blk(TPB);
    // step 1: all 2N landmarks per batch  -> B * 4096/16 = 1024 blocks
    deform_kernel<1><<<dim3(B * (2 * N / PPB)), blk, 0, stream>>>(
        momentum, source_init, target_init, sigmaV2, shape1, out);
    // step 2: target half only            -> B * 2048/16 = 512 blocks
    deform_kernel<2><<<dim3(B * (N / PPB)), blk, 0, stream>>>(
        momentum, source_init, target_init, sigmaV2, shape1, out);
}